// Round 1
// baseline (38215.137 us; speedup 1.0000x reference)
//
#include <hip/hip_runtime.h>
#include <hip/hip_bf16.h>
#include <hip/hip_cooperative_groups.h>

namespace cg = cooperative_groups;

#define T_ 512
#define B_ 64
#define I_ 128
#define H_ 256
#define G_ 768   // 3H
#define L_ 6
#define M_ (T_ * B_)   // 32768

typedef __attribute__((ext_vector_type(8))) short short8;
typedef __attribute__((ext_vector_type(4))) float f32x4;

__device__ __forceinline__ ushort f2bf(float x) {
    union { float f; unsigned u; } v; v.f = x;
    unsigned r = v.u + 0x7FFFu + ((v.u >> 16) & 1u);
    return (ushort)(r >> 16);
}
__device__ __forceinline__ float bf2f(ushort h) {
    union { unsigned u; float f; } v; v.u = ((unsigned)h) << 16;
    return v.f;
}

// dst[m][k] = bf16( src[m][ (k%rows)*cols + k/rows ] )  -- the _eff reinterpretation
__global__ void k_transpose_cast(const float* __restrict__ src, ushort* __restrict__ dst,
                                 int rows, int cols, long total) {
    long i = (long)blockIdx.x * blockDim.x + threadIdx.x;
    long stride = (long)gridDim.x * blockDim.x;
    long per = (long)rows * cols;
    for (; i < total; i += stride) {
        long m = i / per, k = i - m * per;
        long r = k % rows, c = k / rows;
        dst[i] = f2bf(src[m * per + r * cols + c]);
    }
}

__global__ void k_cast(const float* __restrict__ src, ushort* __restrict__ dst, long n) {
    long i = (long)blockIdx.x * blockDim.x + threadIdx.x;
    long stride = (long)gridDim.x * blockDim.x;
    for (; i < n; i += stride) dst[i] = f2bf(src[i]);
}

// gi[dir][m][g] = sum_k A[m][k] * E[dir][g][k] + bias[dir][g], stored bf16
__global__ __launch_bounds__(256)
void k_gi_gemm(const ushort* __restrict__ A,    // [M][K] bf16
               const ushort* __restrict__ E,    // [2][768][K] bf16
               const float* __restrict__ bias,  // [2][768]
               ushort* __restrict__ gi,         // [2][M][768] bf16
               int K) {
    int dir = blockIdx.z;
    const ushort* Bd = E + (long)dir * G_ * K;
    const float* bs = bias + dir * G_;
    ushort* gid = gi + (long)dir * (long)M_ * G_;

    int m0 = blockIdx.x * 64, n0 = blockIdx.y * 64;
    int lane = threadIdx.x & 63, w = threadIdx.x >> 6;
    int r16 = lane & 15, koff = (lane >> 4) * 8;

    const ushort* Arow = A + (long)(m0 + w * 16 + r16) * K + koff;
    f32x4 acc[4] = {{0.f,0.f,0.f,0.f},{0.f,0.f,0.f,0.f},{0.f,0.f,0.f,0.f},{0.f,0.f,0.f,0.f}};

    for (int k0 = 0; k0 < K; k0 += 32) {
        short8 a = *(const short8*)(Arow + k0);
#pragma unroll
        for (int nt = 0; nt < 4; nt++) {
            short8 b = *(const short8*)(Bd + (long)(n0 + nt * 16 + r16) * K + k0 + koff);
            acc[nt] = __builtin_amdgcn_mfma_f32_16x16x32_bf16(a, b, acc[nt], 0, 0, 0);
        }
    }
#pragma unroll
    for (int nt = 0; nt < 4; nt++) {
        int col = n0 + nt * 16 + r16;
        float bsv = bs[col];
#pragma unroll
        for (int j = 0; j < 4; j++) {
            int row = m0 + w * 16 + (lane >> 4) * 4 + j;
            gid[(long)row * G_ + col] = f2bf(acc[nt][j] + bsv);
        }
    }
}

// Cooperative scan: 32 WGs (16 per direction), each WG owns 16 h-columns.
// Whh fragments held in registers; h state ping-pongs in global (bf16).
#define HPAD 264
__global__ __launch_bounds__(256)
void k_scan(const ushort* __restrict__ gi,   // [2][M][768] bf16
            const ushort* __restrict__ Ehh,  // [2][768][256] bf16 (this layer)
            const float* __restrict__ bhh,   // [2][768]
            const float* __restrict__ h0,    // [2][64][256] (this layer)
            ushort* __restrict__ hbuf,       // [2][2][64*256] bf16 ping-pong
            ushort* __restrict__ out_bf,     // Xbuf (layers 0..4)
            float* __restrict__ out_f,       // d_out (layer 5)
            int is_last) {
    cg::grid_group grid = cg::this_grid();
    int bx = blockIdx.x;
    int dir = bx >> 4, slice = bx & 15, js = slice * 16;
    int tid = threadIdx.x, lane = tid & 63, w = tid >> 6;
    int r16 = lane & 15, koff = (lane >> 4) * 8;
    int bb = w * 16;

    const ushort* gid = gi + (long)dir * (long)M_ * G_;
    const ushort* Ed = Ehh + (long)dir * G_ * H_;
    const float* bhd = bhh + dir * G_;
    ushort* hping = hbuf + dir * 2 * (B_ * H_);
    ushort* hpong = hping + (B_ * H_);

    __shared__ ushort hlds[B_ * HPAD];

    // Load Whh fragments (held in registers for all 512 steps)
    short8 bfrag[3][8];
#pragma unroll
    for (int nt = 0; nt < 3; nt++)
#pragma unroll
        for (int ks = 0; ks < 8; ks++)
            bfrag[nt][ks] = *(const short8*)(Ed + (long)(nt * H_ + js + r16) * H_ + ks * 32 + koff);

    float bh[3];
#pragma unroll
    for (int nt = 0; nt < 3; nt++) bh[nt] = bhd[nt * H_ + js + r16];

    // init h ping from h0 (this WG's 16-column slice)
    {
        int b = tid >> 2, j4 = (tid & 3) * 4;
#pragma unroll
        for (int i = 0; i < 4; i++)
            hping[b * H_ + js + j4 + i] =
                f2bf(h0[(long)dir * B_ * H_ + b * H_ + js + j4 + i]);
    }
    __threadfence();
    grid.sync();

    for (int s = 0; s < T_; s++) {
        int t = dir ? (T_ - 1 - s) : s;
        const ushort* hsrc = (s & 1) ? hpong : hping;
        ushort* hdst = (s & 1) ? hping : hpong;

        // stage full h into LDS (padded rows)
        {
            int r = tid >> 2, c = (tid & 3) * 64;
#pragma unroll
            for (int k8 = 0; k8 < 8; k8++)
                *(short8*)&hlds[r * HPAD + c + k8 * 8] =
                    *(const short8*)(hsrc + r * H_ + c + k8 * 8);
        }

        // issue gi loads early (12 scattered bf16 per lane)
        float giv[3][4];
#pragma unroll
        for (int nt = 0; nt < 3; nt++)
#pragma unroll
            for (int j = 0; j < 4; j++) {
                int b = bb + (lane >> 4) * 4 + j;
                giv[nt][j] = bf2f(gid[(long)(t * B_ + b) * G_ + nt * H_ + js + r16]);
            }

        __syncthreads();

        // gh = h @ Whh^T for this WG's 48 output rows
        f32x4 acc[3] = {{0.f,0.f,0.f,0.f},{0.f,0.f,0.f,0.f},{0.f,0.f,0.f,0.f}};
#pragma unroll
        for (int ks = 0; ks < 8; ks++) {
            short8 a = *(const short8*)&hlds[(bb + r16) * HPAD + ks * 32 + koff];
#pragma unroll
            for (int nt = 0; nt < 3; nt++)
                acc[nt] = __builtin_amdgcn_mfma_f32_16x16x32_bf16(a, bfrag[nt][ks], acc[nt], 0, 0, 0);
        }

        // gates + state update (all in-lane: same (row,col) across the 3 gate tiles)
#pragma unroll
        for (int j = 0; j < 4; j++) {
            int b = bb + (lane >> 4) * 4 + j;
            float hr = acc[0][j] + bh[0];
            float hz = acc[1][j] + bh[1];
            float hn = acc[2][j] + bh[2];
            float r = 1.f / (1.f + __expf(-(giv[0][j] + hr)));
            float z = 1.f / (1.f + __expf(-(giv[1][j] + hz)));
            float n = tanhf(giv[2][j] + r * hn);
            float hold = bf2f(hlds[b * HPAD + js + r16]);
            float hnew = (1.f - z) * n + z * hold;
            hdst[b * H_ + js + r16] = f2bf(hnew);
            long orow = (long)(t * B_ + b) * (2 * H_) + dir * H_ + js + r16;
            if (is_last) out_f[orow] = hnew;
            else out_bf[orow] = f2bf(hnew);
        }
        __threadfence();
        grid.sync();
    }
}

extern "C" void kernel_launch(void* const* d_in, const int* in_sizes, int n_in,
                              void* d_out, int out_size, void* d_ws, size_t ws_size,
                              hipStream_t stream) {
    const float* x      = (const float*)d_in[0];
    const float* h0     = (const float*)d_in[1];
    const float* w_ih_0 = (const float*)d_in[2];
    const float* w_hh_0 = (const float*)d_in[3];
    const float* b_ih_0 = (const float*)d_in[4];
    const float* b_hh_0 = (const float*)d_in[5];
    const float* w_ih_r = (const float*)d_in[6];
    const float* w_hh_r = (const float*)d_in[7];
    const float* b_ih_r = (const float*)d_in[8];
    const float* b_hh_r = (const float*)d_in[9];
    float* out = (float*)d_out;

    char* ws = (char*)d_ws;
    size_t off = 0;
    auto alloc = [&](size_t bytes) -> void* {
        void* p = ws + off;
        off = (off + bytes + 255) & ~(size_t)255;
        return p;
    };
    ushort* Ehh  = (ushort*)alloc(12L * G_ * H_ * 2);        // [6][2][768][256]
    ushort* Eih0 = (ushort*)alloc(2L * G_ * I_ * 2);         // [2][768][128]
    ushort* EihR = (ushort*)alloc(10L * G_ * 512 * 2);       // [5][2][768][512]
    ushort* gi   = (ushort*)alloc(2L * M_ * G_ * 2);         // [2][32768][768]
    ushort* Xbuf = (ushort*)alloc((long)M_ * 512 * 2);       // [32768][512]
    ushort* hbuf = (ushort*)alloc(2L * 2 * B_ * H_ * 2);     // [2][2][64*256]

    // weight prep (the _eff reinterpretation) + bf16 cast
    k_transpose_cast<<<dim3(512),  256, 0, stream>>>(w_hh_0, Ehh,                 G_, H_,  2L * G_ * H_);
    k_transpose_cast<<<dim3(2048), 256, 0, stream>>>(w_hh_r, Ehh + 2L * G_ * H_,  G_, H_, 10L * G_ * H_);
    k_transpose_cast<<<dim3(512),  256, 0, stream>>>(w_ih_0, Eih0,                G_, I_,  2L * G_ * I_);
    k_transpose_cast<<<dim3(2048), 256, 0, stream>>>(w_ih_r, EihR,                G_, 512, 10L * G_ * 512);
    k_cast<<<dim3(2048), 256, 0, stream>>>(x, Xbuf, (long)M_ * I_);

    for (int l = 0; l < L_; l++) {
        int K = (l == 0) ? I_ : 512;
        const ushort* Eih = (l == 0) ? Eih0 : (EihR + (long)(l - 1) * 2 * G_ * 512);
        const float* bih = (l == 0) ? b_ih_0 : (b_ih_r + (long)(l - 1) * 2 * G_);
        const float* bhh = (l == 0) ? b_hh_0 : (b_hh_r + (long)(l - 1) * 2 * G_);
        const ushort* Ehl = Ehh + (long)l * 2 * G_ * H_;
        const float* h0l = h0 + (long)l * 2 * B_ * H_;

        k_gi_gemm<<<dim3(M_ / 64, G_ / 64, 2), 256, 0, stream>>>(Xbuf, Eih, bih, gi, K);

        int is_last = (l == L_ - 1);
        const ushort* gi_a = gi;
        const ushort* Ehl_a = Ehl;
        const float* bhh_a = bhh;
        const float* h0l_a = h0l;
        ushort* hbuf_a = hbuf;
        ushort* outbf_a = Xbuf;
        float* outf_a = out;
        void* args[] = {
            (void*)&gi_a, (void*)&Ehl_a, (void*)&bhh_a, (void*)&h0l_a,
            (void*)&hbuf_a, (void*)&outbf_a, (void*)&outf_a, (void*)&is_last
        };
        hipLaunchCooperativeKernel((const void*)k_scan, dim3(32), dim3(256), args, 0, stream);
    }
}

// Round 2
// 14512.051 us; speedup vs baseline: 2.6333x; 2.6333x over previous
//
#include <hip/hip_runtime.h>
#include <hip/hip_bf16.h>

#define T_ 512
#define B_ 64
#define I_ 128
#define H_ 256
#define G_ 768   // 3H
#define L_ 6
#define M_ (T_ * B_)   // 32768

typedef __attribute__((ext_vector_type(8))) short short8;
typedef __attribute__((ext_vector_type(4))) float f32x4;
typedef __attribute__((ext_vector_type(4))) unsigned short us4;

__device__ __forceinline__ ushort f2bf(float x) {
    union { float f; unsigned u; } v; v.f = x;
    unsigned r = v.u + 0x7FFFu + ((v.u >> 16) & 1u);
    return (ushort)(r >> 16);
}
__device__ __forceinline__ float bf2f(ushort h) {
    union { unsigned u; float f; } v; v.u = ((unsigned)h) << 16;
    return v.f;
}
__device__ __forceinline__ float fast_rcp(float x) {
#if __has_builtin(__builtin_amdgcn_rcpf)
    return __builtin_amdgcn_rcpf(x);
#else
    return 1.0f / x;
#endif
}

// dst[m][k] = bf16( src[m][ (k%rows)*cols + k/rows ] )  -- the _eff reinterpretation
__global__ void k_transpose_cast(const float* __restrict__ src, ushort* __restrict__ dst,
                                 int rows, int cols, long total) {
    long i = (long)blockIdx.x * blockDim.x + threadIdx.x;
    long stride = (long)gridDim.x * blockDim.x;
    long per = (long)rows * cols;
    for (; i < total; i += stride) {
        long m = i / per, k = i - m * per;
        long r = k % rows, c = k / rows;
        dst[i] = f2bf(src[m * per + r * cols + c]);
    }
}

__global__ void k_cast(const float* __restrict__ src, ushort* __restrict__ dst, long n) {
    long i = (long)blockIdx.x * blockDim.x + threadIdx.x;
    long stride = (long)gridDim.x * blockDim.x;
    for (; i < n; i += stride) dst[i] = f2bf(src[i]);
}

// gi[dir][t][g][b] = sum_k A[t*64+b][k] * E[dir][g][k] + b_ih[g] + (g<2H ? b_hh[g] : 0)
// Transposed+packed output so the scan can load 4 consecutive b per lane (8B).
__global__ __launch_bounds__(256)
void k_gi_gemm(const ushort* __restrict__ A,    // [M][K] bf16
               const ushort* __restrict__ E,    // [2][768][K] bf16
               const float* __restrict__ bih,   // [2][768]
               const float* __restrict__ bhh,   // [2][768]
               ushort* __restrict__ gi,         // [2][T][768][64] bf16
               int K) {
    int dir = blockIdx.z;
    const ushort* Bd = E + (long)dir * G_ * K;
    const float* bi = bih + dir * G_;
    const float* bh = bhh + dir * G_;
    ushort* gid = gi + (long)dir * T_ * G_ * B_;

    int t = blockIdx.x;
    int m0 = t * 64, n0 = blockIdx.y * 64;
    int lane = threadIdx.x & 63, w = threadIdx.x >> 6;
    int r16 = lane & 15, koff = (lane >> 4) * 8;

    const ushort* Arow = A + (long)(m0 + w * 16 + r16) * K + koff;
    f32x4 acc[4] = {{0.f,0.f,0.f,0.f},{0.f,0.f,0.f,0.f},{0.f,0.f,0.f,0.f},{0.f,0.f,0.f,0.f}};

    for (int k0 = 0; k0 < K; k0 += 32) {
        short8 a = *(const short8*)(Arow + k0);
#pragma unroll
        for (int nt = 0; nt < 4; nt++) {
            short8 b = *(const short8*)(Bd + (long)(n0 + nt * 16 + r16) * K + k0 + koff);
            acc[nt] = __builtin_amdgcn_mfma_f32_16x16x32_bf16(a, b, acc[nt], 0, 0, 0);
        }
    }
#pragma unroll
    for (int nt = 0; nt < 4; nt++) {
        int col = n0 + nt * 16 + r16;
        float bias = bi[col] + (col < 2 * H_ ? bh[col] : 0.f);
        us4 pk;
#pragma unroll
        for (int j = 0; j < 4; j++) pk[j] = f2bf(acc[nt][j] + bias);
        *(us4*)(gid + ((long)t * G_ + col) * B_ + w * 16 + (lane >> 4) * 4) = pk;
    }
}

// Batch-split scan: grid = 8 WGs (dir = bx>>2, btile = bx&3). WG = 512 thr = 8 waves.
// Each WG owns 16 batch rows; h lives in double-buffered swizzled LDS; Whh in VGPRs.
// No inter-WG communication (batch elements are independent).
__global__ __launch_bounds__(512, 2)
void k_scan(const ushort* __restrict__ gi,   // [2][T][768][64] bf16
            const ushort* __restrict__ Ehh,  // [2][768][256] bf16 (this layer)
            const float* __restrict__ bhh,   // [2][768]
            const float* __restrict__ h0,    // [2][64][256] f32 (this layer)
            ushort* __restrict__ out_bf,     // Xbuf [M][512] (layers 0..4)
            float* __restrict__ out_f,       // d_out [M][512] (layer 5)
            int is_last) {
    int bx = blockIdx.x;
    int dir = bx >> 2, b0 = (bx & 3) * 16;
    int tid = threadIdx.x, lane = tid & 63, w = tid >> 6;
    int r16 = lane & 15, q = lane >> 4;
    int js = w * 32;

    const ushort* gid = gi + (long)dir * T_ * G_ * B_;
    const ushort* Ed  = Ehh + (long)dir * G_ * H_;
    const float*  bhd = bhh + dir * G_;
    const float*  h0d = h0 + (long)dir * B_ * H_;

    __shared__ ushort hl[2][16 * 256];   // 16 KiB, XOR-swizzled rows (512 B each)

    // Whh fragments: wave owns 32 h-cols -> 3 gates x 2 col-tiles x 8 k-steps
    short8 bfrag[3][2][8];
#pragma unroll
    for (int nt = 0; nt < 3; nt++)
#pragma unroll
        for (int ct = 0; ct < 2; ct++) {
            int g = nt * H_ + js + ct * 16 + r16;
#pragma unroll
            for (int ks = 0; ks < 8; ks++)
                bfrag[nt][ct][ks] = *(const short8*)(Ed + (long)g * H_ + ks * 32 + q * 8);
        }

    float bhn[2];
#pragma unroll
    for (int ct = 0; ct < 2; ct++) bhn[ct] = bhd[2 * H_ + js + ct * 16 + r16];

    // init LDS h[0] (swizzled) from h0
    {
        int row = tid >> 5, c0 = (tid & 31) * 8;
        const float* src = h0d + (long)(b0 + row) * H_ + c0;
        union { ushort u[8]; short8 v; } pk;
#pragma unroll
        for (int i = 0; i < 8; i++) pk.u[i] = f2bf(src[i]);
        char* dst = (char*)&hl[0][0] + row * 512 + ((c0 * 2) ^ ((row & 7) << 4));
        *(short8*)dst = pk.v;
    }
    // h_old registers (f32) for the z-blend: rows q*4+j, cols js+ct*16+r16
    float hprev[2][4];
#pragma unroll
    for (int ct = 0; ct < 2; ct++)
#pragma unroll
        for (int j = 0; j < 4; j++)
            hprev[ct][j] = h0d[(long)(b0 + q * 4 + j) * H_ + js + ct * 16 + r16];
    __syncthreads();

    int sw = (r16 & 7) << 4;
    for (int s = 0; s < T_; s++) {
        int t = dir ? (T_ - 1 - s) : s;
        const char* hc = (const char*)&hl[s & 1][0];
        char* hn_ = (char*)&hl[(s & 1) ^ 1][0];

        // issue gi loads early (consumed after MFMA)
        us4 gv[3][2];
#pragma unroll
        for (int nt = 0; nt < 3; nt++)
#pragma unroll
            for (int ct = 0; ct < 2; ct++) {
                int g = nt * H_ + js + ct * 16 + r16;
                gv[nt][ct] = *(const us4*)(gid + ((long)t * G_ + g) * B_ + b0 + q * 4);
            }

        // gh = h @ Whh^T ; n-gate bias pre-loaded into accumulator
        f32x4 acc[3][2];
#pragma unroll
        for (int ct = 0; ct < 2; ct++) {
            acc[0][ct] = (f32x4){0.f, 0.f, 0.f, 0.f};
            acc[1][ct] = (f32x4){0.f, 0.f, 0.f, 0.f};
            acc[2][ct] = (f32x4){bhn[ct], bhn[ct], bhn[ct], bhn[ct]};
        }
#pragma unroll
        for (int ks = 0; ks < 8; ks++) {
            short8 a = *(const short8*)(hc + r16 * 512 + ((ks * 64 + q * 16) ^ sw));
#pragma unroll
            for (int nt = 0; nt < 3; nt++)
#pragma unroll
                for (int ct = 0; ct < 2; ct++)
                    acc[nt][ct] = __builtin_amdgcn_mfma_f32_16x16x32_bf16(a, bfrag[nt][ct][ks], acc[nt][ct], 0, 0, 0);
        }

        // gates + state update; write h_new to other LDS buffer + global out
#pragma unroll
        for (int ct = 0; ct < 2; ct++) {
            int col = js + ct * 16 + r16;
#pragma unroll
            for (int j = 0; j < 4; j++) {
                int row = q * 4 + j;
                float xr = acc[0][ct][j] + bf2f(gv[0][ct][j]);
                float xz = acc[1][ct][j] + bf2f(gv[1][ct][j]);
                float r = fast_rcp(1.f + __expf(-xr));
                float z = fast_rcp(1.f + __expf(-xz));
                float xn = bf2f(gv[2][ct][j]) + r * acc[2][ct][j];
                float n = 1.f - 2.f * fast_rcp(__expf(2.f * xn) + 1.f);  // tanh
                float hnew = n + z * (hprev[ct][j] - n);
                hprev[ct][j] = hnew;
                ushort us = f2bf(hnew);
                *(ushort*)(hn_ + row * 512 + ((col * 2) ^ ((row & 7) << 4))) = us;
                long orow = ((long)t * B_ + b0 + row) * (2 * H_) + dir * H_ + col;
                if (is_last) out_f[orow] = hnew;
                else out_bf[orow] = us;
            }
        }
        __syncthreads();
    }
}

extern "C" void kernel_launch(void* const* d_in, const int* in_sizes, int n_in,
                              void* d_out, int out_size, void* d_ws, size_t ws_size,
                              hipStream_t stream) {
    const float* x      = (const float*)d_in[0];
    const float* h0     = (const float*)d_in[1];
    const float* w_ih_0 = (const float*)d_in[2];
    const float* w_hh_0 = (const float*)d_in[3];
    const float* b_ih_0 = (const float*)d_in[4];
    const float* b_hh_0 = (const float*)d_in[5];
    const float* w_ih_r = (const float*)d_in[6];
    const float* w_hh_r = (const float*)d_in[7];
    const float* b_ih_r = (const float*)d_in[8];
    const float* b_hh_r = (const float*)d_in[9];
    float* out = (float*)d_out;

    char* ws = (char*)d_ws;
    size_t off = 0;
    auto alloc = [&](size_t bytes) -> void* {
        void* p = ws + off;
        off = (off + bytes + 255) & ~(size_t)255;
        return p;
    };
    ushort* Ehh  = (ushort*)alloc(12L * G_ * H_ * 2);        // [6][2][768][256]
    ushort* Eih0 = (ushort*)alloc(2L * G_ * I_ * 2);         // [2][768][128]
    ushort* EihR = (ushort*)alloc(10L * G_ * 512 * 2);       // [5][2][768][512]
    ushort* gi   = (ushort*)alloc(2L * T_ * G_ * B_ * 2);    // [2][512][768][64]
    ushort* Xbuf = (ushort*)alloc((long)M_ * 512 * 2);       // [32768][512]

    // weight prep (the _eff reinterpretation) + bf16 cast
    k_transpose_cast<<<dim3(512),  256, 0, stream>>>(w_hh_0, Ehh,                 G_, H_,  2L * G_ * H_);
    k_transpose_cast<<<dim3(2048), 256, 0, stream>>>(w_hh_r, Ehh + 2L * G_ * H_,  G_, H_, 10L * G_ * H_);
    k_transpose_cast<<<dim3(512),  256, 0, stream>>>(w_ih_0, Eih0,                G_, I_,  2L * G_ * I_);
    k_transpose_cast<<<dim3(2048), 256, 0, stream>>>(w_ih_r, EihR,                G_, 512, 10L * G_ * 512);
    k_cast<<<dim3(2048), 256, 0, stream>>>(x, Xbuf, (long)M_ * I_);

    for (int l = 0; l < L_; l++) {
        int K = (l == 0) ? I_ : 512;
        const ushort* Eih = (l == 0) ? Eih0 : (EihR + (long)(l - 1) * 2 * G_ * 512);
        const float* bih = (l == 0) ? b_ih_0 : (b_ih_r + (long)(l - 1) * 2 * G_);
        const float* bhh = (l == 0) ? b_hh_0 : (b_hh_r + (long)(l - 1) * 2 * G_);
        const ushort* Ehl = Ehh + (long)l * 2 * G_ * H_;
        const float* h0l = h0 + (long)l * 2 * B_ * H_;

        k_gi_gemm<<<dim3(T_, G_ / 64, 2), 256, 0, stream>>>(Xbuf, Eih, bih, bhh, gi, K);

        int is_last = (l == L_ - 1);
        k_scan<<<dim3(8), dim3(512), 0, stream>>>(gi, Ehl, bhh, h0l, Xbuf, out, is_last);
    }
}

// Round 3
// 13971.274 us; speedup vs baseline: 2.7353x; 1.0387x over previous
//
#include <hip/hip_runtime.h>
#include <hip/hip_bf16.h>

#define T_ 512
#define B_ 64
#define I_ 128
#define H_ 256
#define G_ 768   // 3H
#define L_ 6
#define M_ (T_ * B_)   // 32768

typedef __attribute__((ext_vector_type(8))) short short8;
typedef __attribute__((ext_vector_type(4))) float f32x4;
typedef __attribute__((ext_vector_type(4))) unsigned short us4;

__device__ __forceinline__ ushort f2bf(float x) {
    union { float f; unsigned u; } v; v.f = x;
    unsigned r = v.u + 0x7FFFu + ((v.u >> 16) & 1u);
    return (ushort)(r >> 16);
}
__device__ __forceinline__ float bf2f(ushort h) {
    union { unsigned u; float f; } v; v.u = ((unsigned)h) << 16;
    return v.f;
}
__device__ __forceinline__ float fast_rcp(float x) {
#if __has_builtin(__builtin_amdgcn_rcpf)
    return __builtin_amdgcn_rcpf(x);
#else
    return 1.0f / x;
#endif
}
// barrier without vmcnt(0) drain: LDS-visible only; global stores float across steps
__device__ __forceinline__ void wg_barrier() {
    asm volatile("s_waitcnt lgkmcnt(0)" ::: "memory");
    __builtin_amdgcn_s_barrier();
    asm volatile("" ::: "memory");
}

// dst[m][k] = bf16( src[m][ (k%768)*cols + k/768 ] ) -- the _eff reinterpretation
// grid.z = matrix index m; rows fixed at 768 so div/mod use magic-mul.
__global__ void k_transpose_cast(const float* __restrict__ src, ushort* __restrict__ dst,
                                 int cols) {
    long per = 768L * cols;
    long m = blockIdx.z;
    for (long k = (long)blockIdx.x * blockDim.x + threadIdx.x; k < per;
         k += (long)gridDim.x * blockDim.x) {
        long r = k % 768, c = k / 768;
        dst[m * per + k] = f2bf(src[m * per + r * cols + c]);
    }
}

__global__ void k_cast(const float* __restrict__ src, ushort* __restrict__ dst, long n) {
    long i = (long)blockIdx.x * blockDim.x + threadIdx.x;
    long stride = (long)gridDim.x * blockDim.x;
    for (; i < n; i += stride) dst[i] = f2bf(src[i]);
}

// gi layout per dir: [t][bt(4)][ws(8)][nt*2+ct(6)][r(16)][bq(16)] bf16
// so the scan reads 6 blocks at immediate offsets off one per-thread pointer.
__global__ __launch_bounds__(256)
void k_gi_gemm(const ushort* __restrict__ A,    // [M][K] bf16
               const ushort* __restrict__ E,    // [2][768][K] bf16
               const float* __restrict__ bih,   // [2][768]
               const float* __restrict__ bhh,   // [2][768]
               ushort* __restrict__ gi,
               int K) {
    int dir = blockIdx.z;
    const ushort* Bd = E + (long)dir * G_ * K;
    const float* bi = bih + dir * G_;
    const float* bh = bhh + dir * G_;
    ushort* gid = gi + (long)dir * T_ * G_ * B_;

    int t = blockIdx.x;
    int n0 = blockIdx.y * 64;
    int lane = threadIdx.x & 63, w = threadIdx.x >> 6;
    int r16 = lane & 15, q = lane >> 4, koff = q * 8;

    const ushort* Arow = A + (long)(t * 64 + w * 16 + r16) * K + koff;
    const ushort* Brow[4];
#pragma unroll
    for (int nt = 0; nt < 4; nt++)
        Brow[nt] = Bd + (long)(n0 + nt * 16 + r16) * K + koff;

    f32x4 acc[4] = {{0.f,0.f,0.f,0.f},{0.f,0.f,0.f,0.f},{0.f,0.f,0.f,0.f},{0.f,0.f,0.f,0.f}};

    // register double-buffered K loop
    short8 a = *(const short8*)Arow;
    short8 b[4];
#pragma unroll
    for (int nt = 0; nt < 4; nt++) b[nt] = *(const short8*)Brow[nt];

    for (int k0 = 0; k0 < K; k0 += 32) {
        int kn = (k0 + 32 < K) ? (k0 + 32) : 0;   // safe dummy on last iter
        short8 an = *(const short8*)(Arow + kn);
        short8 bn[4];
#pragma unroll
        for (int nt = 0; nt < 4; nt++) bn[nt] = *(const short8*)(Brow[nt] + kn);
#pragma unroll
        for (int nt = 0; nt < 4; nt++)
            acc[nt] = __builtin_amdgcn_mfma_f32_16x16x32_bf16(a, b[nt], acc[nt], 0, 0, 0);
        a = an;
#pragma unroll
        for (int nt = 0; nt < 4; nt++) b[nt] = bn[nt];
    }

#pragma unroll
    for (int nt = 0; nt < 4; nt++) {
        int col = n0 + nt * 16 + r16;
        float bias = bi[col] + (col < 2 * H_ ? bh[col] : 0.f);
        us4 pk;
#pragma unroll
        for (int j = 0; j < 4; j++) pk[j] = f2bf(acc[nt][j] + bias);
        int gate = col >> 8, c = col & 255;
        int ws = c >> 5, ct = (c >> 4) & 1, r = c & 15;
        long idx = ((((long)t * 4 + w) * 8 + ws) * 6 + gate * 2 + ct) * 256 + r * 16 + q * 4;
        *(us4*)(gid + idx) = pk;
    }
}

// Batch-split scan: 8 WGs (dir = bx>>2, btile = bx&3), 512 thr = 8 waves.
// Whh resident in VGPRs (launch_bounds(512,1) -> 256 VGPR budget).
__global__ __launch_bounds__(512, 1)
void k_scan(const ushort* __restrict__ gi,
            const ushort* __restrict__ Ehh,  // [2][768][256] bf16 (this layer)
            const float* __restrict__ bhh,   // [2][768]
            const float* __restrict__ h0,    // [2][64][256] f32 (this layer)
            ushort* __restrict__ out_bf,     // Xbuf [M][512] (layers 0..4)
            float* __restrict__ out_f,       // d_out [M][512] (layer 5)
            int is_last) {
    int bx = blockIdx.x;
    int dir = bx >> 2, bt = bx & 3, b0 = bt * 16;
    int tid = threadIdx.x, lane = tid & 63, w = tid >> 6;
    int r16 = lane & 15, q = lane >> 4;
    int js = w * 32;

    const ushort* gid = gi + (long)dir * T_ * G_ * B_;
    const ushort* Ed  = Ehh + (long)dir * G_ * H_;
    const float*  bhd = bhh + dir * G_;
    const float*  h0d = h0 + (long)dir * B_ * H_;

    __shared__ ushort hl[2][16 * 256];   // 16 KiB, XOR-swizzled 512B rows

    // Whh fragments: wave owns 32 h-cols -> 3 gates x 2 col-tiles x 8 k-steps
    short8 bfrag[3][2][8];
#pragma unroll
    for (int nt = 0; nt < 3; nt++)
#pragma unroll
        for (int ct = 0; ct < 2; ct++) {
            int g = nt * H_ + js + ct * 16 + r16;
#pragma unroll
            for (int ks = 0; ks < 8; ks++)
                bfrag[nt][ct][ks] = *(const short8*)(Ed + (long)g * H_ + ks * 32 + q * 8);
        }

    float bhn[2];
#pragma unroll
    for (int ct = 0; ct < 2; ct++) bhn[ct] = bhd[2 * H_ + js + ct * 16 + r16];

    // init LDS h[0] (swizzled) from h0
    {
        int row = tid >> 5, c0 = (tid & 31) * 8;
        const float* src = h0d + (long)(b0 + row) * H_ + c0;
        union { ushort u[8]; short8 v; } pk;
#pragma unroll
        for (int i = 0; i < 8; i++) pk.u[i] = f2bf(src[i]);
        char* dst = (char*)&hl[0][0] + row * 512 + ((c0 * 2) ^ ((row & 7) << 4));
        *(short8*)dst = pk.v;
    }
    float hprev[2][4];
#pragma unroll
    for (int ct = 0; ct < 2; ct++)
#pragma unroll
        for (int j = 0; j < 4; j++)
            hprev[ct][j] = h0d[(long)(b0 + q * 4 + j) * H_ + js + ct * 16 + r16];
    wg_barrier();

    int t0 = dir ? (T_ - 1) : 0;
    long gstep = dir ? -(long)(4 * 8 * 6 * 256) : (long)(4 * 8 * 6 * 256);
    const ushort* gbase = gid + (((long)t0 * 4 + bt) * 8 + w) * 6 * 256 + r16 * 16 + q * 4;

    // lagged coalesced output bounce pointers (row = tid>>5, i16 = tid&31)
    int brow = tid >> 5, i16 = tid & 31;
    long xstep = dir ? -(long)B_ * 512 : (long)B_ * 512;
    ushort* xp = out_bf + ((long)t0 * B_ + b0 + brow) * 512 + dir * H_ + i16 * 8;
    float*  fp = out_f  + ((long)t0 * B_ + b0 + brow) * 512 + dir * H_ + i16 * 8;
    int bnc_off = brow * 512 + ((i16 * 16) ^ ((brow & 7) << 4));

    int sw = (r16 & 7) << 4;
    for (int s = 0; s < T_; s++) {
        const char* hc = (const char*)&hl[s & 1][0];
        char* hn_ = (char*)&hl[(s & 1) ^ 1][0];

        // gi loads for this step (6 x 8B at immediate offsets)
        us4 gv[3][2];
#pragma unroll
        for (int nt = 0; nt < 3; nt++)
#pragma unroll
            for (int ct = 0; ct < 2; ct++)
                gv[nt][ct] = *(const us4*)(gbase + (nt * 2 + ct) * 256);
        gbase += gstep;

        // bounce previous step's h (in hc) to global, coalesced 16B/thread
        if (s) {
            short8 v = *(const short8*)(hc + bnc_off);
            if (is_last) {
                union { short8 v; ushort u[8]; } pk; pk.v = v;
                f32x4 f0, f1;
#pragma unroll
                for (int i = 0; i < 4; i++) { f0[i] = bf2f(pk.u[i]); f1[i] = bf2f(pk.u[4 + i]); }
                *(f32x4*)fp = f0; *(f32x4*)(fp + 4) = f1;
            } else {
                *(short8*)xp = v;
            }
            xp += xstep; fp += xstep;
        }

        // gh = h @ Whh^T ; n-gate bias preloaded
        f32x4 acc[3][2];
#pragma unroll
        for (int ct = 0; ct < 2; ct++) {
            acc[0][ct] = (f32x4){0.f, 0.f, 0.f, 0.f};
            acc[1][ct] = (f32x4){0.f, 0.f, 0.f, 0.f};
            acc[2][ct] = (f32x4){bhn[ct], bhn[ct], bhn[ct], bhn[ct]};
        }
#pragma unroll
        for (int ks = 0; ks < 8; ks++) {
            short8 a = *(const short8*)(hc + r16 * 512 + ((ks * 64 + q * 16) ^ sw));
#pragma unroll
            for (int nt = 0; nt < 3; nt++)
#pragma unroll
                for (int ct = 0; ct < 2; ct++)
                    acc[nt][ct] = __builtin_amdgcn_mfma_f32_16x16x32_bf16(a, bfrag[nt][ct][ks], acc[nt][ct], 0, 0, 0);
        }

        // gates + state update; h_new -> other LDS buffer (swizzled)
#pragma unroll
        for (int ct = 0; ct < 2; ct++) {
            int col = js + ct * 16 + r16;
#pragma unroll
            for (int j = 0; j < 4; j++) {
                int row = q * 4 + j;
                float xr = acc[0][ct][j] + bf2f(gv[0][ct][j]);
                float xz = acc[1][ct][j] + bf2f(gv[1][ct][j]);
                float r = fast_rcp(1.f + __expf(-xr));
                float z = fast_rcp(1.f + __expf(-xz));
                float xn = bf2f(gv[2][ct][j]) + r * acc[2][ct][j];
                float n = 1.f - 2.f * fast_rcp(__expf(2.f * xn) + 1.f);  // tanh
                float hnew = n + z * (hprev[ct][j] - n);
                hprev[ct][j] = hnew;
                *(ushort*)(hn_ + row * 512 + ((col * 2) ^ ((row & 7) << 4))) = f2bf(hnew);
            }
        }
        wg_barrier();
    }

    // final bounce: h(T-1) sits in hl[0] (512 steps flipped buffers evenly)
    {
        const char* hc = (const char*)&hl[0][0];
        short8 v = *(const short8*)(hc + bnc_off);
        if (is_last) {
            union { short8 v; ushort u[8]; } pk; pk.v = v;
            f32x4 f0, f1;
#pragma unroll
            for (int i = 0; i < 4; i++) { f0[i] = bf2f(pk.u[i]); f1[i] = bf2f(pk.u[4 + i]); }
            *(f32x4*)fp = f0; *(f32x4*)(fp + 4) = f1;
        } else {
            *(short8*)xp = v;
        }
    }
}

extern "C" void kernel_launch(void* const* d_in, const int* in_sizes, int n_in,
                              void* d_out, int out_size, void* d_ws, size_t ws_size,
                              hipStream_t stream) {
    const float* x      = (const float*)d_in[0];
    const float* h0     = (const float*)d_in[1];
    const float* w_ih_0 = (const float*)d_in[2];
    const float* w_hh_0 = (const float*)d_in[3];
    const float* b_ih_0 = (const float*)d_in[4];
    const float* b_hh_0 = (const float*)d_in[5];
    const float* w_ih_r = (const float*)d_in[6];
    const float* w_hh_r = (const float*)d_in[7];
    const float* b_ih_r = (const float*)d_in[8];
    const float* b_hh_r = (const float*)d_in[9];
    float* out = (float*)d_out;

    char* ws = (char*)d_ws;
    size_t off = 0;
    auto alloc = [&](size_t bytes) -> void* {
        void* p = ws + off;
        off = (off + bytes + 255) & ~(size_t)255;
        return p;
    };
    ushort* Ehh  = (ushort*)alloc(12L * G_ * H_ * 2);        // [6][2][768][256]
    ushort* Eih0 = (ushort*)alloc(2L * G_ * I_ * 2);         // [2][768][128]
    ushort* EihR = (ushort*)alloc(10L * G_ * 512 * 2);       // [5][2][768][512]
    ushort* gi   = (ushort*)alloc(2L * T_ * G_ * B_ * 2);    // [2][512][768][64] (tiled)
    ushort* Xbuf = (ushort*)alloc((long)M_ * 512 * 2);       // [32768][512]

    k_transpose_cast<<<dim3(256, 1, 2),  256, 0, stream>>>(w_hh_0, Ehh, H_);
    k_transpose_cast<<<dim3(256, 1, 10), 256, 0, stream>>>(w_hh_r, Ehh + 2L * G_ * H_, H_);
    k_transpose_cast<<<dim3(128, 1, 2),  256, 0, stream>>>(w_ih_0, Eih0, I_);
    k_transpose_cast<<<dim3(512, 1, 10), 256, 0, stream>>>(w_ih_r, EihR, 512);
    k_cast<<<dim3(2048), 256, 0, stream>>>(x, Xbuf, (long)M_ * I_);

    for (int l = 0; l < L_; l++) {
        int K = (l == 0) ? I_ : 512;
        const ushort* Eih = (l == 0) ? Eih0 : (EihR + (long)(l - 1) * 2 * G_ * 512);
        const float* bih = (l == 0) ? b_ih_0 : (b_ih_r + (long)(l - 1) * 2 * G_);
        const float* bhh = (l == 0) ? b_hh_0 : (b_hh_r + (long)(l - 1) * 2 * G_);
        const ushort* Ehl = Ehh + (long)l * 2 * G_ * H_;
        const float* h0l = h0 + (long)l * 2 * B_ * H_;

        k_gi_gemm<<<dim3(T_, G_ / 64, 2), 256, 0, stream>>>(Xbuf, Eih, bih, bhh, gi, K);

        int is_last = (l == L_ - 1);
        k_scan<<<dim3(8), dim3(512), 0, stream>>>(gi, Ehl, bhh, h0l, Xbuf, out, is_last);
    }
}

// Round 4
// 13211.339 us; speedup vs baseline: 2.8926x; 1.0575x over previous
//
#include <hip/hip_runtime.h>
#include <hip/hip_bf16.h>

#define T_ 512
#define B_ 64
#define I_ 128
#define H_ 256
#define G_ 768   // 3H
#define L_ 6
#define M_ (T_ * B_)   // 32768

typedef __attribute__((ext_vector_type(8))) short short8;
typedef __attribute__((ext_vector_type(4))) float f32x4;
typedef __attribute__((ext_vector_type(4))) unsigned short us4;

__device__ __forceinline__ ushort f2bf(float x) {
    union { float f; unsigned u; } v; v.f = x;
    unsigned r = v.u + 0x7FFFu + ((v.u >> 16) & 1u);
    return (ushort)(r >> 16);
}
__device__ __forceinline__ float bf2f(ushort h) {
    union { unsigned u; float f; } v; v.u = ((unsigned)h) << 16;
    return v.f;
}
__device__ __forceinline__ float fast_rcp(float x) {
#if __has_builtin(__builtin_amdgcn_rcpf)
    return __builtin_amdgcn_rcpf(x);
#else
    return 1.0f / x;
#endif
}
// barrier without vmcnt(0) drain: LDS-visible only; global stores float across steps
__device__ __forceinline__ void wg_barrier() {
    asm volatile("s_waitcnt lgkmcnt(0)" ::: "memory");
    __builtin_amdgcn_s_barrier();
    asm volatile("" ::: "memory");
}

// dst[m][k] = bf16( src[m][ (k%768)*cols + k/768 ] ) -- the _eff reinterpretation
__global__ void k_transpose_cast(const float* __restrict__ src, ushort* __restrict__ dst,
                                 int cols) {
    long per = 768L * cols;
    long m = blockIdx.z;
    for (long k = (long)blockIdx.x * blockDim.x + threadIdx.x; k < per;
         k += (long)gridDim.x * blockDim.x) {
        long r = k % 768, c = k / 768;
        dst[m * per + k] = f2bf(src[m * per + r * cols + c]);
    }
}

__global__ void k_cast(const float* __restrict__ src, ushort* __restrict__ dst, long n) {
    long i = (long)blockIdx.x * blockDim.x + threadIdx.x;
    long stride = (long)gridDim.x * blockDim.x;
    for (; i < n; i += stride) dst[i] = f2bf(src[i]);
}

// gi layout per dir: [t][bt(4)][ws(8)][nt*2+ct(6)][r(16)][bq(16)] bf16
__global__ __launch_bounds__(256)
void k_gi_gemm(const ushort* __restrict__ A,    // [M][K] bf16
               const ushort* __restrict__ E,    // [2][768][K] bf16
               const float* __restrict__ bih,   // [2][768]
               const float* __restrict__ bhh,   // [2][768]
               ushort* __restrict__ gi,
               int K) {
    int dir = blockIdx.z;
    const ushort* Bd = E + (long)dir * G_ * K;
    const float* bi = bih + dir * G_;
    const float* bh = bhh + dir * G_;
    ushort* gid = gi + (long)dir * T_ * G_ * B_;

    int t = blockIdx.x;
    int n0 = blockIdx.y * 64;
    int lane = threadIdx.x & 63, w = threadIdx.x >> 6;
    int r16 = lane & 15, q = lane >> 4, koff = q * 8;

    const ushort* Arow = A + (long)(t * 64 + w * 16 + r16) * K + koff;
    const ushort* Brow[4];
#pragma unroll
    for (int nt = 0; nt < 4; nt++)
        Brow[nt] = Bd + (long)(n0 + nt * 16 + r16) * K + koff;

    f32x4 acc[4] = {{0.f,0.f,0.f,0.f},{0.f,0.f,0.f,0.f},{0.f,0.f,0.f,0.f},{0.f,0.f,0.f,0.f}};

    short8 a = *(const short8*)Arow;
    short8 b[4];
#pragma unroll
    for (int nt = 0; nt < 4; nt++) b[nt] = *(const short8*)Brow[nt];

    for (int k0 = 0; k0 < K; k0 += 32) {
        int kn = (k0 + 32 < K) ? (k0 + 32) : 0;
        short8 an = *(const short8*)(Arow + kn);
        short8 bn[4];
#pragma unroll
        for (int nt = 0; nt < 4; nt++) bn[nt] = *(const short8*)(Brow[nt] + kn);
#pragma unroll
        for (int nt = 0; nt < 4; nt++)
            acc[nt] = __builtin_amdgcn_mfma_f32_16x16x32_bf16(a, b[nt], acc[nt], 0, 0, 0);
        a = an;
#pragma unroll
        for (int nt = 0; nt < 4; nt++) b[nt] = bn[nt];
    }

#pragma unroll
    for (int nt = 0; nt < 4; nt++) {
        int col = n0 + nt * 16 + r16;
        float bias = bi[col] + (col < 2 * H_ ? bh[col] : 0.f);
        us4 pk;
#pragma unroll
        for (int j = 0; j < 4; j++) pk[j] = f2bf(acc[nt][j] + bias);
        int gate = col >> 8, c = col & 255;
        int ws = c >> 5, ct = (c >> 4) & 1, r = c & 15;
        long idx = ((((long)t * 4 + w) * 8 + ws) * 6 + gate * 2 + ct) * 256 + r * 16 + q * 4;
        *(us4*)(gid + idx) = pk;
    }
}

// Batch-split scan: 8 WGs (dir = bx>>2, btile = bx&3), 512 thr = 8 waves.
// Per-thread register budget (2 waves/SIMD -> 256): bfrag 192 + acc 24 + gv 12
// + hprev(bf16) 4 + bhn 2 + ptrs/temps ~12  ->  ~246. template<IS_LAST> keeps
// only one output path live.
template<int IS_LAST>
__global__ __launch_bounds__(512, 2)
void k_scan(const ushort* __restrict__ gi,
            const ushort* __restrict__ Ehh,  // [2][768][256] bf16 (this layer)
            const float* __restrict__ bhh,   // [2][768]
            const float* __restrict__ h0,    // [2][64][256] f32 (this layer)
            ushort* __restrict__ out_bf,     // Xbuf [M][512] (layers 0..4)
            float* __restrict__ out_f) {     // d_out [M][512] (layer 5)
    int bx = blockIdx.x;
    int dir = bx >> 2, bt = bx & 3, b0 = bt * 16;
    int tid = threadIdx.x, lane = tid & 63, w = tid >> 6;
    int r16 = lane & 15, q = lane >> 4;
    int js = w * 32;

    const ushort* gid = gi + (long)dir * T_ * G_ * B_;
    const ushort* Ed  = Ehh + (long)dir * G_ * H_;
    const float*  bhd = bhh + dir * G_;
    const float*  h0d = h0 + (long)dir * B_ * H_;

    __shared__ ushort hl[2][16 * 256];   // 16 KiB, XOR-swizzled 512B rows

    // Whh fragments: wave owns 32 h-cols -> 3 gates x 2 col-tiles x 8 k-steps
    short8 bfrag[3][2][8];
#pragma unroll
    for (int nt = 0; nt < 3; nt++)
#pragma unroll
        for (int ct = 0; ct < 2; ct++) {
            int g = nt * H_ + js + ct * 16 + r16;
#pragma unroll
            for (int ks = 0; ks < 8; ks++)
                bfrag[nt][ct][ks] = *(const short8*)(Ed + (long)g * H_ + ks * 32 + q * 8);
        }

    float bhn[2];
#pragma unroll
    for (int ct = 0; ct < 2; ct++) bhn[ct] = bhd[2 * H_ + js + ct * 16 + r16];

    // init LDS h[0] (swizzled) from h0
    {
        int row = tid >> 5, c0 = (tid & 31) * 8;
        const float* src = h0d + (long)(b0 + row) * H_ + c0;
        union { ushort u[8]; short8 v; } pk;
#pragma unroll
        for (int i = 0; i < 8; i++) pk.u[i] = f2bf(src[i]);
        char* dst = (char*)&hl[0][0] + row * 512 + ((c0 * 2) ^ ((row & 7) << 4));
        *(short8*)dst = pk.v;
    }
    // h_old carried per-lane as packed bf16 (same precision as the LDS copy)
    us4 hprev[2];
#pragma unroll
    for (int ct = 0; ct < 2; ct++) {
        us4 tmp;
#pragma unroll
        for (int j = 0; j < 4; j++)
            tmp[j] = f2bf(h0d[(long)(b0 + q * 4 + j) * H_ + js + ct * 16 + r16]);
        hprev[ct] = tmp;
    }
    wg_barrier();

    int t0 = dir ? (T_ - 1) : 0;
    long gstep = dir ? -(long)(4 * 8 * 6 * 256) : (long)(4 * 8 * 6 * 256);
    const ushort* gbase = gid + (((long)t0 * 4 + bt) * 8 + w) * 6 * 256 + r16 * 16 + q * 4;

    int brow = tid >> 5, i16 = tid & 31;
    long xstep = dir ? -(long)B_ * 512 : (long)B_ * 512;
    ushort* xp = out_bf + ((long)t0 * B_ + b0 + brow) * 512 + dir * H_ + i16 * 8;
    float*  fp = out_f  + ((long)t0 * B_ + b0 + brow) * 512 + dir * H_ + i16 * 8;
    int bnc_off = brow * 512 + ((i16 * 16) ^ ((brow & 7) << 4));

    int sw = (r16 & 7) << 4;
    for (int s = 0; s < T_; s++) {
        const char* hc = (const char*)&hl[s & 1][0];
        char* hn_ = (char*)&hl[(s & 1) ^ 1][0];

        // gi loads for this step (6 x 8B at immediate offsets), issued early
        us4 gv[3][2];
#pragma unroll
        for (int nt = 0; nt < 3; nt++)
#pragma unroll
            for (int ct = 0; ct < 2; ct++)
                gv[nt][ct] = *(const us4*)(gbase + (nt * 2 + ct) * 256);
        gbase += gstep;

        // bounce previous step's h (in hc) to global, coalesced
        if (s) {
            short8 v = *(const short8*)(hc + bnc_off);
            if (IS_LAST) {
                union { short8 v; ushort u[8]; } pk; pk.v = v;
                f32x4 f0, f1;
#pragma unroll
                for (int i = 0; i < 4; i++) { f0[i] = bf2f(pk.u[i]); f1[i] = bf2f(pk.u[4 + i]); }
                *(f32x4*)fp = f0; *(f32x4*)(fp + 4) = f1;
                fp += xstep;
            } else {
                *(short8*)xp = v;
                xp += xstep;
            }
        }

        // gh = h @ Whh^T ; n-gate bias preloaded
        f32x4 acc[3][2];
#pragma unroll
        for (int ct = 0; ct < 2; ct++) {
            acc[0][ct] = (f32x4){0.f, 0.f, 0.f, 0.f};
            acc[1][ct] = (f32x4){0.f, 0.f, 0.f, 0.f};
            acc[2][ct] = (f32x4){bhn[ct], bhn[ct], bhn[ct], bhn[ct]};
        }
#pragma unroll
        for (int ks = 0; ks < 8; ks++) {
            short8 a = *(const short8*)(hc + r16 * 512 + ((ks * 64 + q * 16) ^ sw));
#pragma unroll
            for (int nt = 0; nt < 3; nt++)
#pragma unroll
                for (int ct = 0; ct < 2; ct++)
                    acc[nt][ct] = __builtin_amdgcn_mfma_f32_16x16x32_bf16(a, bfrag[nt][ct][ks], acc[nt][ct], 0, 0, 0);
        }

        // gates + state update; h_new -> other LDS buffer (swizzled)
#pragma unroll
        for (int ct = 0; ct < 2; ct++) {
            int col = js + ct * 16 + r16;
#pragma unroll
            for (int j = 0; j < 4; j++) {
                int row = q * 4 + j;
                float xr = acc[0][ct][j] + bf2f(gv[0][ct][j]);
                float xz = acc[1][ct][j] + bf2f(gv[1][ct][j]);
                float r = fast_rcp(1.f + __expf(-xr));
                float z = fast_rcp(1.f + __expf(-xz));
                float xn = bf2f(gv[2][ct][j]) + r * acc[2][ct][j];
                float n = 1.f - 2.f * fast_rcp(__expf(2.f * xn) + 1.f);  // tanh
                float hnew = n + z * (bf2f(hprev[ct][j]) - n);
                ushort us = f2bf(hnew);
                hprev[ct][j] = us;
                *(ushort*)(hn_ + row * 512 + ((col * 2) ^ ((row & 7) << 4))) = us;
            }
        }
        wg_barrier();
    }

    // final bounce: h(T-1) sits in hl[0]
    {
        const char* hc = (const char*)&hl[0][0];
        short8 v = *(const short8*)(hc + bnc_off);
        if (IS_LAST) {
            union { short8 v; ushort u[8]; } pk; pk.v = v;
            f32x4 f0, f1;
#pragma unroll
            for (int i = 0; i < 4; i++) { f0[i] = bf2f(pk.u[i]); f1[i] = bf2f(pk.u[4 + i]); }
            *(f32x4*)fp = f0; *(f32x4*)(fp + 4) = f1;
        } else {
            *(short8*)xp = v;
        }
    }
}

extern "C" void kernel_launch(void* const* d_in, const int* in_sizes, int n_in,
                              void* d_out, int out_size, void* d_ws, size_t ws_size,
                              hipStream_t stream) {
    const float* x      = (const float*)d_in[0];
    const float* h0     = (const float*)d_in[1];
    const float* w_ih_0 = (const float*)d_in[2];
    const float* w_hh_0 = (const float*)d_in[3];
    const float* b_ih_0 = (const float*)d_in[4];
    const float* b_hh_0 = (const float*)d_in[5];
    const float* w_ih_r = (const float*)d_in[6];
    const float* w_hh_r = (const float*)d_in[7];
    const float* b_ih_r = (const float*)d_in[8];
    const float* b_hh_r = (const float*)d_in[9];
    float* out = (float*)d_out;

    char* ws = (char*)d_ws;
    size_t off = 0;
    auto alloc = [&](size_t bytes) -> void* {
        void* p = ws + off;
        off = (off + bytes + 255) & ~(size_t)255;
        return p;
    };
    ushort* Ehh  = (ushort*)alloc(12L * G_ * H_ * 2);        // [6][2][768][256]
    ushort* Eih0 = (ushort*)alloc(2L * G_ * I_ * 2);         // [2][768][128]
    ushort* EihR = (ushort*)alloc(10L * G_ * 512 * 2);       // [5][2][768][512]
    ushort* gi   = (ushort*)alloc(2L * T_ * G_ * B_ * 2);    // [2][512][768][64] (tiled)
    ushort* Xbuf = (ushort*)alloc((long)M_ * 512 * 2);       // [32768][512]

    k_transpose_cast<<<dim3(256, 1, 2),  256, 0, stream>>>(w_hh_0, Ehh, H_);
    k_transpose_cast<<<dim3(256, 1, 10), 256, 0, stream>>>(w_hh_r, Ehh + 2L * G_ * H_, H_);
    k_transpose_cast<<<dim3(128, 1, 2),  256, 0, stream>>>(w_ih_0, Eih0, I_);
    k_transpose_cast<<<dim3(512, 1, 10), 256, 0, stream>>>(w_ih_r, EihR, 512);
    k_cast<<<dim3(2048), 256, 0, stream>>>(x, Xbuf, (long)M_ * I_);

    for (int l = 0; l < L_; l++) {
        int K = (l == 0) ? I_ : 512;
        const ushort* Eih = (l == 0) ? Eih0 : (EihR + (long)(l - 1) * 2 * G_ * 512);
        const float* bih = (l == 0) ? b_ih_0 : (b_ih_r + (long)(l - 1) * 2 * G_);
        const float* bhh = (l == 0) ? b_hh_0 : (b_hh_r + (long)(l - 1) * 2 * G_);
        const ushort* Ehl = Ehh + (long)l * 2 * G_ * H_;
        const float* h0l = h0 + (long)l * 2 * B_ * H_;

        k_gi_gemm<<<dim3(T_, G_ / 64, 2), 256, 0, stream>>>(Xbuf, Eih, bih, bhh, gi, K);

        if (l == L_ - 1)
            k_scan<1><<<dim3(8), dim3(512), 0, stream>>>(gi, Ehl, bhh, h0l, Xbuf, out);
        else
            k_scan<0><<<dim3(8), dim3(512), 0, stream>>>(gi, Ehl, bhh, h0l, Xbuf, out);
    }
}